// Round 8
// baseline (84.629 us; speedup 1.0000x reference)
//
#include <hip/hip_runtime.h>
#include <hip/hip_bf16.h>

// CoreAttention B=2 S=2048 H=16 D=64, f32 in/out, causal. Flash-attn fwd,
// bf16 MFMA 16x16x32. R8 = R7 (dual concurrent Q-tiles (u,31-u) per block,
// shared K-frags/V-stage/V-tr, perfect 33-tile balance) with the SOFTP P-write
// fixed to use a proper LDS pointer (R7 dereferenced a truncated flat address
// -> memory fault). Integer LDS addresses are used ONLY inside ds_read asm.

typedef __attribute__((ext_vector_type(8))) short short8;
typedef __attribute__((ext_vector_type(4))) short short4v;
typedef __attribute__((ext_vector_type(4))) float f32x4;

__device__ __forceinline__ unsigned cvtpk(float a, float b) {
    __hip_bfloat162 h = __float22bfloat162_rn(make_float2(a, b));
    union { __hip_bfloat162 h; unsigned u; } c; c.h = h;
    return c.u;
}

__device__ __forceinline__ short8 pack8(float4 a, float4 b) {
    union { short8 s; unsigned u[4]; } w;
    w.u[0] = cvtpk(a.x, a.y); w.u[1] = cvtpk(a.z, a.w);
    w.u[2] = cvtpk(b.x, b.y); w.u[3] = cvtpk(b.z, b.w);
    return w.s;
}

#define TR64(dst, addr) \
    asm volatile("ds_read_b64_tr_b16 %0, %1" : "=v"(dst) : "v"(addr))

__global__ __launch_bounds__(256, 2)
void CoreAttention_68710886801875_kernel(const float* __restrict__ Q,
                                         const float* __restrict__ K,
                                         const float* __restrict__ V,
                                         float* __restrict__ O)
{
    constexpr int S = 2048, HD = 1024;
    constexpr float SCALE = 0.125f * 1.44269504088896340736f;  // 1/sqrt(64)*log2(e)

    __shared__ __align__(16) unsigned short ldsK[2][64 * 64];     // [k][d] XOR-swizzled
    __shared__ __align__(16) unsigned short ldsV[2][64 * 64];     // [k/4][d/16][4][16]
    __shared__ __align__(16) unsigned short ldsPT[4][2][64 * 16]; // [wave][tile] subtiled

    const int tid = threadIdx.x;
    const int wid = tid >> 6, lane = tid & 63, g = lane >> 4, lm = lane & 15;

    // XCD-chunked swizzle; co-resident blocks (bx, bx+256) -> wg, wg+32: same u.
    const int bx = blockIdx.x;
    const int wg = ((bx & 7) << 6) | (bx >> 3);
    const int u  = wg & 15;            // tile pair (u, 31-u) in 64-row units
    const int h  = (wg >> 4) & 15;
    const int b  = wg >> 8;
    const int q0A = u << 6;
    const int q0B = (31 - u) << 6;
    const int ntMax = 32 - u;          // tile B's KV-tile count; A's = u+1
    const size_t base = ((size_t)b * S) * HD + (size_t)h * 64;

    // ---- staging geometry: rows {r0, r0+32}, cols c8*8..c8*8+7
    const int r0 = tid >> 3, c8 = tid & 7;
    const float* kp0 = K + base + (size_t)r0 * HD + c8 * 8;
    const float* vp0 = V + base + (size_t)r0 * HD + c8 * 8;
    float4 kst[4], vst[4];

    auto ISSUE = [&](int k0) {
        const float* kp = kp0 + (size_t)k0 * HD;
        const float* vp = vp0 + (size_t)k0 * HD;
        kst[0] = *(const float4*)kp;
        kst[1] = *(const float4*)(kp + 4);
        kst[2] = *(const float4*)(kp + (size_t)32 * HD);
        kst[3] = *(const float4*)(kp + (size_t)32 * HD + 4);
        vst[0] = *(const float4*)vp;
        vst[1] = *(const float4*)(vp + 4);
        vst[2] = *(const float4*)(vp + (size_t)32 * HD);
        vst[3] = *(const float4*)(vp + (size_t)32 * HD + 4);
    };
    auto WRITE = [&](int buf) {
#pragma unroll
        for (int it = 0; it < 2; ++it) {
            const int r = r0 + it * 32;
            const unsigned byteK = (unsigned)((r * 128 + c8 * 16) ^ ((r & 7) << 4));
            *(short8*)((char*)&ldsK[buf][0] + byteK) = pack8(kst[it * 2], kst[it * 2 + 1]);
            const unsigned byteV = (unsigned)(((r >> 2) * 4 + (c8 >> 1)) * 128 +
                                              (r & 3) * 32 + (c8 & 1) * 16);
            *(short8*)((char*)&ldsV[buf][0] + byteV) = pack8(vst[it * 2], vst[it * 2 + 1]);
        }
    };

    // ---- Q fragments, both tiles (A-layout: row=lm, k=g*8+j)
    short8 qfA[2], qfB[2];
#pragma unroll
    for (int tile = 0; tile < 2; ++tile) {
        const int q0 = tile ? q0B : q0A;
        const float* qp = Q + base + (size_t)(q0 + wid * 16 + lm) * HD + g * 8;
#pragma unroll
        for (int ks = 0; ks < 2; ++ks) {
            float4 a = *(const float4*)(qp + ks * 32);
            float4 c = *(const float4*)(qp + ks * 32 + 4);
            a.x *= SCALE; a.y *= SCALE; a.z *= SCALE; a.w *= SCALE;
            c.x *= SCALE; c.y *= SCALE; c.z *= SCALE; c.w *= SCALE;
            (tile ? qfB : qfA)[ks] = pack8(a, c);
        }
    }

    f32x4 oaccA[4], oaccB[4];
#pragma unroll
    for (int n = 0; n < 4; ++n) {
        oaccA[n] = (f32x4){0.f, 0.f, 0.f, 0.f};
        oaccB[n] = (f32x4){0.f, 0.f, 0.f, 0.f};
    }
    float mA[4], lA[4], mB[4], lB[4];
#pragma unroll
    for (int r = 0; r < 4; ++r) { mA[r] = -1e30f; lA[r] = 0.f; mB[r] = -1e30f; lB[r] = 0.f; }

    const unsigned vBase = (unsigned)(size_t)&ldsV[0][0];
    const unsigned ptAaddr = (unsigned)(size_t)&ldsPT[wid][0][0];  // asm-only
    const unsigned ptBaddr = ptAaddr + 2048u;                      // asm-only

    // softmax+P for one tile (per-lane lazy l; defer-max THR=8 in log2 domain)
    auto SOFTP = [&](f32x4 (&sv)[4], float (&mr)[4], float (&lr)[4],
                     f32x4 (&oa)[4], unsigned short* ptO) {
        float lmax[4];
        int need = 0;
#pragma unroll
        for (int r = 0; r < 4; ++r) {
            lmax[r] = fmaxf(fmaxf(sv[0][r], sv[1][r]), fmaxf(sv[2][r], sv[3][r]));
            need |= (lmax[r] > mr[r] + 8.f) ? 1 : 0;
        }
        if (__any(need)) {
#pragma unroll
            for (int r = 0; r < 4; ++r) {
                float mx = lmax[r];
#pragma unroll
                for (int msk = 1; msk <= 8; msk <<= 1)
                    mx = fmaxf(mx, __shfl_xor(mx, msk, 64));
                const float mn = fmaxf(mr[r], mx);
                const float corr = exp2f(mr[r] - mn);
                mr[r] = mn;
                lr[r] *= corr;
#pragma unroll
                for (int n = 0; n < 4; ++n) oa[n][r] *= corr;
            }
        }
#pragma unroll
        for (int n = 0; n < 4; ++n) {
            float p[4];
#pragma unroll
            for (int r = 0; r < 4; ++r) {
                p[r] = exp2f(sv[n][r] - mr[r]);
                lr[r] += p[r];
            }
            union { short4v s; unsigned uu[2]; } pk;
            pk.uu[0] = cvtpk(p[0], p[1]);
            pk.uu[1] = cvtpk(p[2], p[3]);
            const unsigned byte = (unsigned)((n * 4 + (lm >> 2)) * 128 +
                                             (lm & 3) * 32 + g * 8);
            *(short4v*)((char*)ptO + byte) = pk.s;   // proper LDS pointer
        }
    };

    ISSUE(0);
    WRITE(0);
    __syncthreads();

    for (int t = 0; t < ntMax; ++t) {
        const int cur = t & 1;
        if (t + 1 < ntMax) ISSUE((t + 1) * 64);

        const bool actA = (t <= u);
        const bool dA = (t == u);
        const bool dB = (t == ntMax - 1);

        // ---- QK^T for both tiles; K fragments shared
        f32x4 svA[4], svB[4];
        __builtin_amdgcn_s_setprio(1);
#pragma unroll
        for (int n = 0; n < 4; ++n) {
            const int kr = n * 16 + lm;
            const unsigned b0 = cur * 8192u +
                (unsigned)((kr * 128 + g * 16) ^ ((kr & 7) << 4));
            const unsigned b1 = cur * 8192u +
                (unsigned)((kr * 128 + 64 + g * 16) ^ ((kr & 7) << 4));
            const short8 kf0 = *(const short8*)((const char*)&ldsK[0][0] + b0);
            const short8 kf1 = *(const short8*)((const char*)&ldsK[0][0] + b1);

            if (actA && (!dA || n <= wid)) {
                f32x4 acc = (f32x4){0.f, 0.f, 0.f, 0.f};
                acc = __builtin_amdgcn_mfma_f32_16x16x32_bf16(qfA[0], kf0, acc, 0, 0, 0);
                acc = __builtin_amdgcn_mfma_f32_16x16x32_bf16(qfA[1], kf1, acc, 0, 0, 0);
                if (dA && n == wid) {
#pragma unroll
                    for (int r = 0; r < 4; ++r)
                        if (lm > g * 4 + r) acc[r] = -1e30f;
                }
                svA[n] = acc;
            } else {
                svA[n] = (f32x4){-1e30f, -1e30f, -1e30f, -1e30f};
            }

            if (!dB || n <= wid) {
                f32x4 acc = (f32x4){0.f, 0.f, 0.f, 0.f};
                acc = __builtin_amdgcn_mfma_f32_16x16x32_bf16(qfB[0], kf0, acc, 0, 0, 0);
                acc = __builtin_amdgcn_mfma_f32_16x16x32_bf16(qfB[1], kf1, acc, 0, 0, 0);
                if (dB && n == wid) {
#pragma unroll
                    for (int r = 0; r < 4; ++r)
                        if (lm > g * 4 + r) acc[r] = -1e30f;
                }
                svB[n] = acc;
            } else {
                svB[n] = (f32x4){-1e30f, -1e30f, -1e30f, -1e30f};
            }
        }
        __builtin_amdgcn_s_setprio(0);

        // ---- softmax + P writes
        if (actA) SOFTP(svA, mA, lA, oaccA, &ldsPT[wid][0][0]);
        SOFTP(svB, mB, lB, oaccB, &ldsPT[wid][1][0]);

        // ---- PV: V tr-reads shared; P tr-reads per tile
        asm volatile("s_waitcnt lgkmcnt(0)" ::: "memory");  // P^T visible
        short4v vlo[2][4], vhi[2][4], paL[2], paH[2], pbL[2], pbH[2];
#pragma unroll
        for (int ks = 0; ks < 2; ++ks) {
            const unsigned sub = (unsigned)(8 * ks + 2 * g);
#pragma unroll
            for (int n = 0; n < 4; ++n) {
                const unsigned va = vBase + cur * 8192u + (sub * 4 + n) * 128 + lm * 8;
                TR64(vlo[ks][n], va);
                TR64(vhi[ks][n], va + 512);
            }
            if (actA) {
                const unsigned pa = ptAaddr + sub * 128 + lm * 8;
                TR64(paL[ks], pa);
                TR64(paH[ks], pa + 128);
            }
            const unsigned pb = ptBaddr + sub * 128 + lm * 8;
            TR64(pbL[ks], pb);
            TR64(pbH[ks], pb + 128);
        }
        asm volatile("s_waitcnt lgkmcnt(0)" ::: "memory");
        __builtin_amdgcn_sched_barrier(0);
        __builtin_amdgcn_s_setprio(1);
#pragma unroll
        for (int ks = 0; ks < 2; ++ks) {
            if (actA) {
                const short8 pf = __builtin_shufflevector(paL[ks], paH[ks],
                                                          0, 1, 2, 3, 4, 5, 6, 7);
#pragma unroll
                for (int n = 0; n < 4; ++n) {
                    const short8 vf = __builtin_shufflevector(vlo[ks][n], vhi[ks][n],
                                                              0, 1, 2, 3, 4, 5, 6, 7);
                    oaccA[n] = __builtin_amdgcn_mfma_f32_16x16x32_bf16(pf, vf, oaccA[n], 0, 0, 0);
                }
            }
            {
                const short8 pf = __builtin_shufflevector(pbL[ks], pbH[ks],
                                                          0, 1, 2, 3, 4, 5, 6, 7);
#pragma unroll
                for (int n = 0; n < 4; ++n) {
                    const short8 vf = __builtin_shufflevector(vlo[ks][n], vhi[ks][n],
                                                              0, 1, 2, 3, 4, 5, 6, 7);
                    oaccB[n] = __builtin_amdgcn_mfma_f32_16x16x32_bf16(pf, vf, oaccB[n], 0, 0, 0);
                }
            }
        }
        __builtin_amdgcn_s_setprio(0);

        if (t + 1 < ntMax) WRITE(cur ^ 1);
        __syncthreads();
    }

    // ---- epilogue: reduce per-lane l partials, normalize, store (both tiles)
#pragma unroll
    for (int tile = 0; tile < 2; ++tile) {
        const int q0 = tile ? q0B : q0A;
        f32x4* oa = tile ? oaccB : oaccA;
        float* lr = tile ? lB : lA;
#pragma unroll
        for (int r = 0; r < 4; ++r) {
            float l = lr[r];
#pragma unroll
            for (int msk = 1; msk <= 8; msk <<= 1)
                l += __shfl_xor(l, msk, 64);
            const float inv = 1.0f / l;
            const int row = q0 + wid * 16 + g * 4 + r;
            float* op = O + base + (size_t)row * HD;
#pragma unroll
            for (int n = 0; n < 4; ++n)
                op[n * 16 + lm] = oa[n][r] * inv;
        }
    }
}

extern "C" void kernel_launch(void* const* d_in, const int* in_sizes, int n_in,
                              void* d_out, int out_size, void* d_ws, size_t ws_size,
                              hipStream_t stream) {
    (void)in_sizes; (void)n_in; (void)out_size; (void)d_ws; (void)ws_size;
    const float* Q = (const float*)d_in[0];
    const float* K = (const float*)d_in[1];
    const float* V = (const float*)d_in[2];
    float* O = (float*)d_out;

    dim3 grid(512);    // B * H * 16 tile-pairs (u, 31-u)
    dim3 block(256);   // 4 waves, two 64-row Q-tiles concurrently
    hipLaunchKernelGGL(CoreAttention_68710886801875_kernel, grid, block, 0, stream,
                       Q, K, V, O);
}

// Round 9
// 80.163 us; speedup vs baseline: 1.0557x; 1.0557x over previous
//
#include <hip/hip_runtime.h>
#include <hip/hip_bf16.h>

// CoreAttention B=2 S=2048 H=16 D=64, f32 in/out, causal. Flash-attn fwd,
// bf16 MFMA 16x16x32. R9 = R8 (dual Q-tiles (u,31-u)/block, perfect balance)
// + pre-pass kernel that converts K/V to bf16 in the EXACT LDS tile-image
// layouts (K XOR-swizzled rows, V tr-subtiled), so the main kernel stages via
// global_load_lds (no cvt/reg/ds_write staging). Falls back to in-kernel
// conversion if ws_size < 16.8MB.

typedef __attribute__((ext_vector_type(8))) short short8;
typedef __attribute__((ext_vector_type(4))) short short4v;
typedef __attribute__((ext_vector_type(4))) float f32x4;

__device__ __forceinline__ unsigned cvtpk(float a, float b) {
    __hip_bfloat162 h = __float22bfloat162_rn(make_float2(a, b));
    union { __hip_bfloat162 h; unsigned u; } c; c.h = h;
    return c.u;
}

__device__ __forceinline__ short8 pack8(float4 a, float4 b) {
    union { short8 s; unsigned u[4]; } w;
    w.u[0] = cvtpk(a.x, a.y); w.u[1] = cvtpk(a.z, a.w);
    w.u[2] = cvtpk(b.x, b.y); w.u[3] = cvtpk(b.z, b.w);
    return w.s;
}

#define TR64(dst, addr) \
    asm volatile("ds_read_b64_tr_b16 %0, %1" : "=v"(dst) : "v"(addr))

#define GLOAD_LDS16(g, l) \
    __builtin_amdgcn_global_load_lds((const __attribute__((address_space(1))) void*)(g), \
                                     (__attribute__((address_space(3))) void*)(l), 16, 0, 0)

// ---- pre-pass: K/V f32 -> bf16 tile images (64x64 tiles, 8192B each)
// K image byte(r,c8) = (r*128 + c8*16) ^ ((r&7)<<4)
// V image byte(k,c8) = ((k>>2)*4 + (c8>>1))*128 + (k&3)*32 + (c8&1)*16
__global__ __launch_bounds__(256, 4)
void CoreAttention_68710886801875_prepass(const float* __restrict__ K,
                                          const float* __restrict__ V,
                                          unsigned short* __restrict__ Kbf,
                                          unsigned short* __restrict__ Vbf)
{
    const int tile = blockIdx.x;          // bh*32 + kt
    const int bh = tile >> 5, kt = tile & 31;
    const size_t base = (size_t)(bh >> 4) * (2048 * 1024) + (size_t)(bh & 15) * 64;
    unsigned short* ktile = Kbf + (size_t)tile * 4096;
    unsigned short* vtile = Vbf + (size_t)tile * 4096;

#pragma unroll
    for (int it = 0; it < 2; ++it) {
        const int c = threadIdx.x + it * 256;   // 16B chunk id, 512 per tile
        {   // K: invert the XOR swizzle
            const int r  = c >> 3;
            const int c8 = (c & 7) ^ (r & 7);
            const float* src = K + base + (size_t)(kt * 64 + r) * 1024 + c8 * 8;
            *(short8*)(ktile + c * 8) = pack8(*(const float4*)src, *(const float4*)(src + 4));
        }
        {   // V: invert the subtile mapping
            const int s = c >> 3, k_lo = (c >> 1) & 3, half = c & 1;
            const int k  = (s >> 2) * 4 + k_lo;
            const int c8 = (s & 3) * 2 + half;
            const float* src = V + base + (size_t)(kt * 64 + k) * 1024 + c8 * 8;
            *(short8*)(vtile + c * 8) = pack8(*(const float4*)src, *(const float4*)(src + 4));
        }
    }
}

template <int PRE>
__global__ __launch_bounds__(256, 2)
void CoreAttention_68710886801875_kernel(const float* __restrict__ Q,
                                         const float* __restrict__ K,
                                         const float* __restrict__ V,
                                         const unsigned short* __restrict__ Kbf,
                                         const unsigned short* __restrict__ Vbf,
                                         float* __restrict__ O)
{
    constexpr int S = 2048, HD = 1024;
    constexpr float SCALE = 0.125f * 1.44269504088896340736f;  // 1/sqrt(64)*log2(e)

    __shared__ __align__(16) unsigned short ldsK[2][64 * 64];     // [k][d] XOR-swizzled
    __shared__ __align__(16) unsigned short ldsV[2][64 * 64];     // [k/4][d/16][4][16]
    __shared__ __align__(16) unsigned short ldsPT[4][2][64 * 16]; // [wave][tile] subtiled

    const int tid = threadIdx.x;
    const int wid = tid >> 6, lane = tid & 63, g = lane >> 4, lm = lane & 15;

    // XCD-chunked swizzle; co-resident blocks (bx, bx+256) -> wg, wg+32: same u.
    const int bx = blockIdx.x;
    const int wg = ((bx & 7) << 6) | (bx >> 3);
    const int u  = wg & 15;            // tile pair (u, 31-u)
    const int h  = (wg >> 4) & 15;
    const int b  = wg >> 8;
    const int bh = b * 16 + h;
    const int q0A = u << 6;
    const int q0B = (31 - u) << 6;
    const int ntMax = 32 - u;          // B's KV-tile count; A's = u+1
    const size_t base = ((size_t)b * S) * HD + (size_t)h * 64;

    // ---- staging (fallback path): rows {r0, r0+32}, cols c8*8..+7
    const int r0 = tid >> 3, c8 = tid & 7;
    const float* kp0 = K + base + (size_t)r0 * HD + c8 * 8;
    const float* vp0 = V + base + (size_t)r0 * HD + c8 * 8;
    float4 kst[4], vst[4];
    const unsigned short* kbfB = Kbf + (size_t)bh * 32 * 4096;
    const unsigned short* vbfB = Vbf + (size_t)bh * 32 * 4096;

    auto STAGE_ISSUE = [&](int k0, int buf) {
        if constexpr (PRE) {
            const unsigned short* ks = kbfB + (size_t)(k0 >> 6) * 4096 + tid * 8;
            const unsigned short* vs = vbfB + (size_t)(k0 >> 6) * 4096 + tid * 8;
            GLOAD_LDS16(ks,        &ldsK[buf][tid * 8]);
            GLOAD_LDS16(ks + 2048, &ldsK[buf][tid * 8 + 2048]);
            GLOAD_LDS16(vs,        &ldsV[buf][tid * 8]);
            GLOAD_LDS16(vs + 2048, &ldsV[buf][tid * 8 + 2048]);
        } else {
            const float* kp = kp0 + (size_t)k0 * HD;
            const float* vp = vp0 + (size_t)k0 * HD;
            kst[0] = *(const float4*)kp;
            kst[1] = *(const float4*)(kp + 4);
            kst[2] = *(const float4*)(kp + (size_t)32 * HD);
            kst[3] = *(const float4*)(kp + (size_t)32 * HD + 4);
            vst[0] = *(const float4*)vp;
            vst[1] = *(const float4*)(vp + 4);
            vst[2] = *(const float4*)(vp + (size_t)32 * HD);
            vst[3] = *(const float4*)(vp + (size_t)32 * HD + 4);
        }
    };
    auto STAGE_WRITE = [&](int buf) {
        if constexpr (!PRE) {
#pragma unroll
            for (int it = 0; it < 2; ++it) {
                const int r = r0 + it * 32;
                const unsigned byteK = (unsigned)((r * 128 + c8 * 16) ^ ((r & 7) << 4));
                *(short8*)((char*)&ldsK[buf][0] + byteK) = pack8(kst[it * 2], kst[it * 2 + 1]);
                const unsigned byteV = (unsigned)(((r >> 2) * 4 + (c8 >> 1)) * 128 +
                                                  (r & 3) * 32 + (c8 & 1) * 16);
                *(short8*)((char*)&ldsV[buf][0] + byteV) = pack8(vst[it * 2], vst[it * 2 + 1]);
            }
        }
    };

    // ---- Q fragments, both tiles (A-layout: row=lm, k=g*8+j)
    short8 qfA[2], qfB[2];
#pragma unroll
    for (int tile = 0; tile < 2; ++tile) {
        const int q0 = tile ? q0B : q0A;
        const float* qp = Q + base + (size_t)(q0 + wid * 16 + lm) * HD + g * 8;
#pragma unroll
        for (int ks = 0; ks < 2; ++ks) {
            float4 a = *(const float4*)(qp + ks * 32);
            float4 c = *(const float4*)(qp + ks * 32 + 4);
            a.x *= SCALE; a.y *= SCALE; a.z *= SCALE; a.w *= SCALE;
            c.x *= SCALE; c.y *= SCALE; c.z *= SCALE; c.w *= SCALE;
            (tile ? qfB : qfA)[ks] = pack8(a, c);
        }
    }

    f32x4 oaccA[4], oaccB[4];
#pragma unroll
    for (int n = 0; n < 4; ++n) {
        oaccA[n] = (f32x4){0.f, 0.f, 0.f, 0.f};
        oaccB[n] = (f32x4){0.f, 0.f, 0.f, 0.f};
    }
    float mA[4], lA[4], mB[4], lB[4];
#pragma unroll
    for (int r = 0; r < 4; ++r) { mA[r] = -1e30f; lA[r] = 0.f; mB[r] = -1e30f; lB[r] = 0.f; }

    const unsigned vBase = (unsigned)(size_t)&ldsV[0][0];
    const unsigned ptAaddr = (unsigned)(size_t)&ldsPT[wid][0][0];  // asm-only
    const unsigned ptBaddr = ptAaddr + 2048u;                      // asm-only

    auto SOFTP = [&](f32x4 (&sv)[4], float (&mr)[4], float (&lr)[4],
                     f32x4 (&oa)[4], unsigned short* ptO) {
        float lmax[4];
        int need = 0;
#pragma unroll
        for (int r = 0; r < 4; ++r) {
            lmax[r] = fmaxf(fmaxf(sv[0][r], sv[1][r]), fmaxf(sv[2][r], sv[3][r]));
            need |= (lmax[r] > mr[r] + 8.f) ? 1 : 0;
        }
        if (__any(need)) {
#pragma unroll
            for (int r = 0; r < 4; ++r) {
                float mx = lmax[r];
#pragma unroll
                for (int msk = 1; msk <= 8; msk <<= 1)
                    mx = fmaxf(mx, __shfl_xor(mx, msk, 64));
                const float mn = fmaxf(mr[r], mx);
                const float corr = exp2f(mr[r] - mn);
                mr[r] = mn;
                lr[r] *= corr;
#pragma unroll
                for (int n = 0; n < 4; ++n) oa[n][r] *= corr;
            }
        }
#pragma unroll
        for (int n = 0; n < 4; ++n) {
            float p[4];
#pragma unroll
            for (int r = 0; r < 4; ++r) {
                p[r] = exp2f(sv[n][r] - mr[r]);
                lr[r] += p[r];
            }
            union { short4v s; unsigned uu[2]; } pk;
            pk.uu[0] = cvtpk(p[0], p[1]);
            pk.uu[1] = cvtpk(p[2], p[3]);
            const unsigned byte = (unsigned)((n * 4 + (lm >> 2)) * 128 +
                                             (lm & 3) * 32 + g * 8);
            *(short4v*)((char*)ptO + byte) = pk.s;
        }
    };

    STAGE_ISSUE(0, 0);
    STAGE_WRITE(0);
    __syncthreads();

    for (int t = 0; t < ntMax; ++t) {
        const int cur = t & 1;
        if (t + 1 < ntMax) STAGE_ISSUE((t + 1) * 64, cur ^ 1);

        const bool actA = (t <= u);
        const bool dA = (t == u);
        const bool dB = (t == ntMax - 1);

        // ---- QK^T for both tiles; K fragments shared
        f32x4 svA[4], svB[4];
        __builtin_amdgcn_s_setprio(1);
#pragma unroll
        for (int n = 0; n < 4; ++n) {
            const int kr = n * 16 + lm;
            const unsigned b0 = cur * 8192u +
                (unsigned)((kr * 128 + g * 16) ^ ((kr & 7) << 4));
            const unsigned b1 = cur * 8192u +
                (unsigned)((kr * 128 + 64 + g * 16) ^ ((kr & 7) << 4));
            const short8 kf0 = *(const short8*)((const char*)&ldsK[0][0] + b0);
            const short8 kf1 = *(const short8*)((const char*)&ldsK[0][0] + b1);

            if (actA && (!dA || n <= wid)) {
                f32x4 acc = (f32x4){0.f, 0.f, 0.f, 0.f};
                acc = __builtin_amdgcn_mfma_f32_16x16x32_bf16(qfA[0], kf0, acc, 0, 0, 0);
                acc = __builtin_amdgcn_mfma_f32_16x16x32_bf16(qfA[1], kf1, acc, 0, 0, 0);
                if (dA && n == wid) {
#pragma unroll
                    for (int r = 0; r < 4; ++r)
                        if (lm > g * 4 + r) acc[r] = -1e30f;
                }
                svA[n] = acc;
            } else {
                svA[n] = (f32x4){-1e30f, -1e30f, -1e30f, -1e30f};
            }

            if (!dB || n <= wid) {
                f32x4 acc = (f32x4){0.f, 0.f, 0.f, 0.f};
                acc = __builtin_amdgcn_mfma_f32_16x16x32_bf16(qfB[0], kf0, acc, 0, 0, 0);
                acc = __builtin_amdgcn_mfma_f32_16x16x32_bf16(qfB[1], kf1, acc, 0, 0, 0);
                if (dB && n == wid) {
#pragma unroll
                    for (int r = 0; r < 4; ++r)
                        if (lm > g * 4 + r) acc[r] = -1e30f;
                }
                svB[n] = acc;
            } else {
                svB[n] = (f32x4){-1e30f, -1e30f, -1e30f, -1e30f};
            }
        }
        __builtin_amdgcn_s_setprio(0);

        // ---- softmax + P writes
        if (actA) SOFTP(svA, mA, lA, oaccA, &ldsPT[wid][0][0]);
        SOFTP(svB, mB, lB, oaccB, &ldsPT[wid][1][0]);

        // ---- PV: V tr-reads shared; P tr-reads per tile
        asm volatile("s_waitcnt lgkmcnt(0)" ::: "memory");  // P^T visible
        short4v vlo[2][4], vhi[2][4], paL[2], paH[2], pbL[2], pbH[2];
#pragma unroll
        for (int ks = 0; ks < 2; ++ks) {
            const unsigned sub = (unsigned)(8 * ks + 2 * g);
#pragma unroll
            for (int n = 0; n < 4; ++n) {
                const unsigned va = vBase + cur * 8192u + (sub * 4 + n) * 128 + lm * 8;
                TR64(vlo[ks][n], va);
                TR64(vhi[ks][n], va + 512);
            }
            if (actA) {
                const unsigned pa = ptAaddr + sub * 128 + lm * 8;
                TR64(paL[ks], pa);
                TR64(paH[ks], pa + 128);
            }
            const unsigned pb = ptBaddr + sub * 128 + lm * 8;
            TR64(pbL[ks], pb);
            TR64(pbH[ks], pb + 128);
        }
        asm volatile("s_waitcnt lgkmcnt(0)" ::: "memory");
        __builtin_amdgcn_sched_barrier(0);
        __builtin_amdgcn_s_setprio(1);
#pragma unroll
        for (int ks = 0; ks < 2; ++ks) {
            if (actA) {
                const short8 pf = __builtin_shufflevector(paL[ks], paH[ks],
                                                          0, 1, 2, 3, 4, 5, 6, 7);
#pragma unroll
                for (int n = 0; n < 4; ++n) {
                    const short8 vf = __builtin_shufflevector(vlo[ks][n], vhi[ks][n],
                                                              0, 1, 2, 3, 4, 5, 6, 7);
                    oaccA[n] = __builtin_amdgcn_mfma_f32_16x16x32_bf16(pf, vf, oaccA[n], 0, 0, 0);
                }
            }
            {
                const short8 pf = __builtin_shufflevector(pbL[ks], pbH[ks],
                                                          0, 1, 2, 3, 4, 5, 6, 7);
#pragma unroll
                for (int n = 0; n < 4; ++n) {
                    const short8 vf = __builtin_shufflevector(vlo[ks][n], vhi[ks][n],
                                                              0, 1, 2, 3, 4, 5, 6, 7);
                    oaccB[n] = __builtin_amdgcn_mfma_f32_16x16x32_bf16(pf, vf, oaccB[n], 0, 0, 0);
                }
            }
        }
        __builtin_amdgcn_s_setprio(0);

        if (t + 1 < ntMax) STAGE_WRITE(cur ^ 1);
        __syncthreads();
    }

    // ---- epilogue: reduce per-lane l partials, normalize, store (both tiles)
#pragma unroll
    for (int tile = 0; tile < 2; ++tile) {
        const int q0 = tile ? q0B : q0A;
        f32x4* oa = tile ? oaccB : oaccA;
        float* lr = tile ? lB : lA;
#pragma unroll
        for (int r = 0; r < 4; ++r) {
            float l = lr[r];
#pragma unroll
            for (int msk = 1; msk <= 8; msk <<= 1)
                l += __shfl_xor(l, msk, 64);
            const float inv = 1.0f / l;
            const int row = q0 + wid * 16 + g * 4 + r;
            float* op = O + base + (size_t)row * HD;
#pragma unroll
            for (int n = 0; n < 4; ++n)
                op[n * 16 + lm] = oa[n][r] * inv;
        }
    }
}

extern "C" void kernel_launch(void* const* d_in, const int* in_sizes, int n_in,
                              void* d_out, int out_size, void* d_ws, size_t ws_size,
                              hipStream_t stream) {
    (void)in_sizes; (void)n_in; (void)out_size;
    const float* Q = (const float*)d_in[0];
    const float* K = (const float*)d_in[1];
    const float* V = (const float*)d_in[2];
    float* O = (float*)d_out;

    const size_t needWs = 2ull * 4194304ull * 2ull;  // K+V bf16 images: 16.8MB
    if (ws_size >= needWs) {
        unsigned short* Kbf = (unsigned short*)d_ws;
        unsigned short* Vbf = Kbf + 4194304;
        hipLaunchKernelGGL(CoreAttention_68710886801875_prepass,
                           dim3(1024), dim3(256), 0, stream, K, V, Kbf, Vbf);
        hipLaunchKernelGGL((CoreAttention_68710886801875_kernel<1>),
                           dim3(512), dim3(256), 0, stream, Q, K, V, Kbf, Vbf, O);
    } else {
        hipLaunchKernelGGL((CoreAttention_68710886801875_kernel<0>),
                           dim3(512), dim3(256), 0, stream, Q, K, V,
                           (const unsigned short*)nullptr, (const unsigned short*)nullptr, O);
    }
}